// Round 2
// baseline (756.147 us; speedup 1.0000x reference)
//
#include <hip/hip_runtime.h>
#include <stdint.h>

#define SEQ    2048
#define HIDDEN 4096
#define NQH    32
#define NKVH   2
#define HD     128
#define QKVN   4608   // (32+4)*128
#define ATTN_N 4096   // 32*128

typedef short bf16x8 __attribute__((ext_vector_type(8)));
typedef float f32x4  __attribute__((ext_vector_type(4)));

__device__ __forceinline__ float bf2f(unsigned short u) {
  union { unsigned int i; float f; } v; v.i = ((unsigned int)u) << 16; return v.f;
}
__device__ __forceinline__ unsigned short f2bf(float f) {
  union { float f; unsigned int i; } v; v.f = f;
  unsigned int r = v.i + 0x7fffu + ((v.i >> 16) & 1u);  // RNE
  return (unsigned short)(r >> 16);
}

// ---- dtype probe: bf16 arrays have sane exponents at every index; fp32 read
// ---- as ushort has uniform-random exponent bits at even indices. flag=1 -> fp32
__global__ void detect_dtype(const unsigned short* __restrict__ hs, int* __restrict__ flag) {
  int bad = 0;
  for (int i = 0; i < 128; i += 2) {
    const int e = (hs[i] >> 7) & 0xFF;
    if (e < 100 || e > 140) bad++;
  }
  *flag = (bad > 16) ? 1 : 0;
}

// ---- canonicalize any input to bf16 (4 elems/thread) ----
__global__ void to_bf16_any(const void* __restrict__ in, unsigned short* __restrict__ out,
                            int n4, const int* __restrict__ flag) {
  const int i = blockIdx.x * blockDim.x + threadIdx.x;
  if (i >= n4) return;
  if (*flag) {
    const float4 f = ((const float4*)in)[i];
    ushort4 u; u.x = f2bf(f.x); u.y = f2bf(f.y); u.z = f2bf(f.z); u.w = f2bf(f.w);
    ((ushort4*)out)[i] = u;
  } else {
    ((ushort4*)out)[i] = ((const ushort4*)in)[i];
  }
}

// ---- canonicalize any input to fp32 (4 elems/thread) ----
__global__ void to_f32_any(const void* __restrict__ in, float* __restrict__ out,
                           int n4, const int* __restrict__ flag) {
  const int i = blockIdx.x * blockDim.x + threadIdx.x;
  if (i >= n4) return;
  if (*flag) {
    ((float4*)out)[i] = ((const float4*)in)[i];
  } else {
    const ushort4 u = ((const ushort4*)in)[i];
    float4 f; f.x = bf2f(u.x); f.y = bf2f(u.y); f.z = bf2f(u.z); f.w = bf2f(u.w);
    ((float4*)out)[i] = f;
  }
}

// ---- transpose + convert: out[c][r] (bf16) = in[r][c]; in is R x C ----
__global__ void transpose_any(const void* __restrict__ in, unsigned short* __restrict__ out,
                              int R, int C, const int* __restrict__ flag) {
  __shared__ unsigned short t[32][36];   // +4 pad breaks bank conflicts
  const int r0 = blockIdx.y * 32, c0 = blockIdx.x * 32;
  const int lr = threadIdx.x >> 3;         // 0..31
  const int lc = (threadIdx.x & 7) << 2;   // 0,4,...,28
  unsigned short v0, v1, v2, v3;
  if (*flag) {
    const float4 f = *(const float4*)((const float*)in + (size_t)(r0 + lr) * C + c0 + lc);
    v0 = f2bf(f.x); v1 = f2bf(f.y); v2 = f2bf(f.z); v3 = f2bf(f.w);
  } else {
    const ushort4 u = *(const ushort4*)((const unsigned short*)in + (size_t)(r0 + lr) * C + c0 + lc);
    v0 = u.x; v1 = u.y; v2 = u.z; v3 = u.w;
  }
  t[lr][lc] = v0; t[lr][lc + 1] = v1; t[lr][lc + 2] = v2; t[lr][lc + 3] = v3;
  __syncthreads();
  unsigned short* op = out + (size_t)(c0 + lr) * R + r0 + lc;
  ushort4 w;
  w.x = t[lc][lr]; w.y = t[lc + 1][lr]; w.z = t[lc + 2][lr]; w.w = t[lc + 3][lr];
  *(ushort4*)op = w;
}

// ------------- C = A(MxK) * Bt(NxK)^T (+bias), bf16 in, fp32 acc --------------
// out dtype: bf16 unless of32 points at nonzero flag. 128x128 tile, BK=32.
__global__ __launch_bounds__(256, 2)
void gemm_bt(const unsigned short* __restrict__ A,
             const unsigned short* __restrict__ Bt,
             const float* __restrict__ bias,
             void* __restrict__ C,
             int M, int N, int K, const int* __restrict__ of32) {
  __shared__ __attribute__((aligned(16))) unsigned short As[128 * 32];
  __shared__ __attribute__((aligned(16))) unsigned short Bs[128 * 32];
  const int tid  = threadIdx.x;
  const int wave = tid >> 6, lane = tid & 63;
  const int quad = lane >> 4, l16 = lane & 15;
  const int m0 = blockIdx.y * 128, n0 = blockIdx.x * 128;
  const int wm = (wave >> 1) * 64, wn = (wave & 1) * 64;

  const int crow = tid >> 2, ck = (tid & 3) << 3;
  const unsigned short* gA = A + (size_t)(m0 + crow) * K + ck;
  const unsigned short* gB = Bt + (size_t)(n0 + crow) * K + ck;
  unsigned short* lA = As + tid * 8;
  unsigned short* lB = Bs + tid * 8;

  f32x4 acc[4][4] = {};

  for (int k0 = 0; k0 < K; k0 += 32) {
    uint4 ra0 = *(const uint4*)(gA + k0);
    uint4 ra1 = *(const uint4*)(gA + (size_t)64 * K + k0);
    uint4 rb0 = *(const uint4*)(gB + k0);
    uint4 rb1 = *(const uint4*)(gB + (size_t)64 * K + k0);
    __syncthreads();                 // prev iter's LDS reads done
    *(uint4*)lA = ra0;
    *(uint4*)(lA + 64 * 32) = ra1;
    *(uint4*)lB = rb0;
    *(uint4*)(lB + 64 * 32) = rb1;
    __syncthreads();                 // tile visible
    bf16x8 aF[4], bF[4];
#pragma unroll
    for (int i = 0; i < 4; i++)
      aF[i] = *(const bf16x8*)&As[(wm + i * 16 + l16) * 32 + quad * 8];
#pragma unroll
    for (int j = 0; j < 4; j++)
      bF[j] = *(const bf16x8*)&Bs[(wn + j * 16 + l16) * 32 + quad * 8];
#pragma unroll
    for (int i = 0; i < 4; i++)
#pragma unroll
      for (int j = 0; j < 4; j++)
        acc[i][j] = __builtin_amdgcn_mfma_f32_16x16x32_bf16(aF[i], bF[j], acc[i][j], 0, 0, 0);
  }

  const int wf32 = of32 ? *of32 : 0;
#pragma unroll
  for (int j = 0; j < 4; j++) {
    const int col = n0 + wn + j * 16 + l16;
    const float bv = bias ? bias[col] : 0.0f;
#pragma unroll
    for (int i = 0; i < 4; i++) {
#pragma unroll
      for (int r = 0; r < 4; r++) {
        const int row = m0 + wm + i * 16 + quad * 4 + r;   // C/D: row=quad*4+reg, col=l16
        const float v = acc[i][j][r] + bv;
        const size_t off = (size_t)row * N + col;
        if (wf32) ((float*)C)[off] = v;
        else      ((unsigned short*)C)[off] = f2bf(v);
      }
    }
  }
}

// --------- RoPE (interleaved) + split into Q (scaled), K, V^T buffers ---------
__global__ void rope_split(const unsigned short* __restrict__ qkv,
                           const float* __restrict__ cosb,
                           const float* __restrict__ sinb,
                           unsigned short* __restrict__ qb,
                           unsigned short* __restrict__ kb,
                           unsigned short* __restrict__ vtb) {
  const int s = blockIdx.x;
  const unsigned short* row = qkv + (size_t)s * QKVN;
  // 1/sqrt(128) * log2(e): softmax runs in exp2 domain
  const float sc = 0.08838834764831845f * 1.44269504088896341f;
  for (int p = threadIdx.x; p < QKVN / 2; p += blockDim.x) {
    const int col = p << 1;
    const int head = col >> 7;
    const int d = col & 127;
    float x0 = bf2f(row[col]), x1 = bf2f(row[col + 1]);
    float y0 = x0, y1 = x1;
    if (d < 64) {
      const float c  = cosb[s * 64 + (d >> 1)];
      const float sn = sinb[s * 64 + (d >> 1)];
      y0 = x0 * c - x1 * sn;
      y1 = x1 * c + x0 * sn;
    }
    if (head < NQH) {
      const size_t o = (size_t)head * SEQ * HD + (size_t)s * HD + d;
      qb[o] = f2bf(y0 * sc); qb[o + 1] = f2bf(y1 * sc);
    } else if (head < NQH + NKVH) {
      const size_t o = (size_t)(head - NQH) * SEQ * HD + (size_t)s * HD + d;
      kb[o] = f2bf(y0); kb[o + 1] = f2bf(y1);
    } else {
      const size_t o = (size_t)(head - NQH - NKVH) * HD * SEQ + (size_t)d * SEQ + s;
      vtb[o] = f2bf(x0); vtb[o + SEQ] = f2bf(x1);  // V: no rope, transposed store
    }
  }
}

// ------------------- causal flash attention, bf16 MFMA ------------------------
// grid (32 heads, 32 q-tiles of 64). 4 waves/block, wave owns 16 q-rows.
// All 4 waves share ktmax == qt, so in-loop __syncthreads is uniform.
__global__ __launch_bounds__(256, 2)
void attn_fwd(const unsigned short* __restrict__ qb,
              const unsigned short* __restrict__ kb,
              const unsigned short* __restrict__ vtb,
              unsigned short* __restrict__ ob) {
  const int h = blockIdx.x;
  const int qt = blockIdx.y;
  const int wave = threadIdx.x >> 6, lane = threadIdx.x & 63;
  const int quad = lane >> 4, l16 = lane & 15;
  const int q0 = qt * 64 + wave * 16;
  const unsigned short* qh  = qb  + (size_t)h * SEQ * HD;
  const unsigned short* kh  = kb  + (size_t)(h >> 4) * SEQ * HD;
  const unsigned short* vth = vtb + (size_t)(h >> 4) * HD * SEQ;
  // wave-private P staging; 80 pitch keeps b128 reads 16B-aligned
  __shared__ __attribute__((aligned(16))) unsigned short plds[4][16][80];

  bf16x8 qf[4];
#pragma unroll
  for (int kbk = 0; kbk < 4; kbk++)   // A-frag: A[m=l16][k=quad*8+j]
    qf[kbk] = *(const bf16x8*)&qh[(size_t)(q0 + l16) * HD + kbk * 32 + quad * 8];

  f32x4 oacc[8] = {};
  float mrow[4] = {-1e30f, -1e30f, -1e30f, -1e30f};
  float lrow[4] = {0.f, 0.f, 0.f, 0.f};

  const int ktmax = qt;               // same for all 4 waves
  for (int kt = 0; kt <= ktmax; kt++) {
    const int kbase = kt * 64;
    f32x4 sv[4] = {};
#pragma unroll
    for (int kbk = 0; kbk < 4; kbk++) {
#pragma unroll
      for (int t = 0; t < 4; t++) {
        // B-frag: B[n=key][k=d] read from K row-major (Bt form)
        bf16x8 kf = *(const bf16x8*)&kh[(size_t)(kbase + t * 16 + l16) * HD + kbk * 32 + quad * 8];
        sv[t] = __builtin_amdgcn_mfma_f32_16x16x32_bf16(qf[kbk], kf, sv[t], 0, 0, 0);
      }
    }
    if (kt == ktmax) {   // only diagonal tile needs masking
#pragma unroll
      for (int t = 0; t < 4; t++) {
        const int key = kbase + t * 16 + l16;
#pragma unroll
        for (int r = 0; r < 4; r++)
          if (key > q0 + quad * 4 + r) sv[t][r] = -1e30f;
      }
    }
    float alpha[4];
#pragma unroll
    for (int r = 0; r < 4; r++) {   // row = q0 + quad*4 + r, replicated over 16 lanes
      float mx = fmaxf(fmaxf(sv[0][r], sv[1][r]), fmaxf(sv[2][r], sv[3][r]));
#pragma unroll
      for (int off = 8; off; off >>= 1) mx = fmaxf(mx, __shfl_xor(mx, off));
      const float mnew = fmaxf(mrow[r], mx);
      alpha[r] = __builtin_exp2f(mrow[r] - mnew);
      mrow[r] = mnew;
      float ls = 0.f;
#pragma unroll
      for (int t = 0; t < 4; t++) {
        const float pv = __builtin_exp2f(sv[t][r] - mnew);
        sv[t][r] = pv;
        ls += pv;
      }
#pragma unroll
      for (int off = 8; off; off >>= 1) ls += __shfl_xor(ls, off);
      lrow[r] = lrow[r] * alpha[r] + ls;
    }
#pragma unroll
    for (int dt = 0; dt < 8; dt++)
#pragma unroll
      for (int r = 0; r < 4; r++) oacc[dt][r] *= alpha[r];
    // P: C-layout -> A-layout via LDS round-trip (barriers: uniform trip count)
    __syncthreads();
#pragma unroll
    for (int r = 0; r < 4; r++)
#pragma unroll
      for (int t = 0; t < 4; t++)
        plds[wave][quad * 4 + r][t * 16 + l16] = f2bf(sv[t][r]);
    __syncthreads();
    bf16x8 pf0 = *(const bf16x8*)&plds[wave][l16][quad * 8];
    bf16x8 pf1 = *(const bf16x8*)&plds[wave][l16][32 + quad * 8];
#pragma unroll
    for (int dt = 0; dt < 8; dt++) {
      const unsigned short* vrow = vth + (size_t)(dt * 16 + l16) * SEQ + kbase;
      bf16x8 vf0 = *(const bf16x8*)(vrow + quad * 8);
      oacc[dt] = __builtin_amdgcn_mfma_f32_16x16x32_bf16(pf0, vf0, oacc[dt], 0, 0, 0);
      bf16x8 vf1 = *(const bf16x8*)(vrow + 32 + quad * 8);
      oacc[dt] = __builtin_amdgcn_mfma_f32_16x16x32_bf16(pf1, vf1, oacc[dt], 0, 0, 0);
    }
  }
#pragma unroll
  for (int dt = 0; dt < 8; dt++) {
#pragma unroll
    for (int r = 0; r < 4; r++) {
      const float v = oacc[dt][r] / lrow[r];
      ob[(size_t)(q0 + quad * 4 + r) * ATTN_N + h * HD + dt * 16 + l16] = f2bf(v);
    }
  }
}

extern "C" void kernel_launch(void* const* d_in, const int* in_sizes, int n_in,
                              void* d_out, int out_size, void* d_ws, size_t ws_size,
                              hipStream_t stream) {
  const void* hs_raw   = d_in[0];
  const void* cos_raw  = d_in[1];
  const void* sin_raw  = d_in[2];
  const void* wqkv_raw = d_in[3];
  const void* bqkv_raw = d_in[4];
  const void* wo_raw   = d_in[5];
  unsigned short* ws = (unsigned short*)d_ws;

  // ws layout (ushort units), phase-aliased; total ~75 MB
  unsigned short* R1   = ws;                       // 18,874,368: wt_qkv -> q/k/vt bufs -> wt_o
  unsigned short* R2   = R1 + (size_t)QKVN * HIDDEN;   // 9,437,184: qkv -> attnb
  unsigned short* hs_c = R2 + (size_t)SEQ * QKVN;      // 8,388,608
  float* cosf  = (float*)(hs_c + (size_t)SEQ * HIDDEN);
  float* sinf  = cosf + SEQ * 64;
  float* biasf = sinf + SEQ * 64;
  int*   flag  = (int*)(biasf + QKVN);

  unsigned short* wt_qkv = R1;
  unsigned short* qbuf   = R1;                                  // after gemm1
  unsigned short* kbuf   = qbuf + (size_t)NQH * SEQ * HD;
  unsigned short* vtbuf  = kbuf + (size_t)NKVH * SEQ * HD;
  unsigned short* wt_o   = R1;                                  // after attn
  unsigned short* qkv    = R2;
  unsigned short* attnb  = R2;                                  // after rope

  detect_dtype<<<1, 1, 0, stream>>>((const unsigned short*)hs_raw, flag);
  to_bf16_any<<<(SEQ * HIDDEN / 4 + 255) / 256, 256, 0, stream>>>(hs_raw, hs_c, SEQ * HIDDEN / 4, flag);
  to_f32_any<<<(SEQ * 64 / 4 + 255) / 256, 256, 0, stream>>>(cos_raw, cosf, SEQ * 64 / 4, flag);
  to_f32_any<<<(SEQ * 64 / 4 + 255) / 256, 256, 0, stream>>>(sin_raw, sinf, SEQ * 64 / 4, flag);
  to_f32_any<<<(QKVN / 4 + 255) / 256, 256, 0, stream>>>(bqkv_raw, biasf, QKVN / 4, flag);

  transpose_any<<<dim3(QKVN / 32, HIDDEN / 32), 256, 0, stream>>>(wqkv_raw, wt_qkv, HIDDEN, QKVN, flag);
  gemm_bt<<<dim3(QKVN / 128, SEQ / 128), 256, 0, stream>>>(hs_c, wt_qkv, biasf, qkv, SEQ, QKVN, HIDDEN, nullptr);
  rope_split<<<SEQ, 256, 0, stream>>>(qkv, cosf, sinf, qbuf, kbuf, vtbuf);
  attn_fwd<<<dim3(NQH, SEQ / 64), 256, 0, stream>>>(qbuf, kbuf, vtbuf, attnb);
  transpose_any<<<dim3(ATTN_N / 32, HIDDEN / 32), 256, 0, stream>>>(wo_raw, wt_o, HIDDEN, ATTN_N, flag);
  gemm_bt<<<dim3(ATTN_N / 128, SEQ / 128), 256, 0, stream>>>(attnb, wt_o, nullptr, d_out, SEQ, ATTN_N, HIDDEN, flag);
}

// Round 4
// 507.045 us; speedup vs baseline: 1.4913x; 1.4913x over previous
//
#include <hip/hip_runtime.h>
#include <stdint.h>

#define SEQ    2048
#define HIDDEN 4096
#define NQH    32
#define NKVH   2
#define HD     128
#define QKVN   4608   // (32+4)*128
#define ATTN_N 4096   // 32*128

typedef short bf16x8 __attribute__((ext_vector_type(8)));
typedef float f32x4  __attribute__((ext_vector_type(4)));

#define ASYNC16(gp, lp) __builtin_amdgcn_global_load_lds( \
    (const __attribute__((address_space(1))) void*)(gp),  \
    (__attribute__((address_space(3))) void*)(lp), 16, 0, 0)

__device__ __forceinline__ float bf2f(unsigned short u) {
  union { unsigned int i; float f; } v; v.i = ((unsigned int)u) << 16; return v.f;
}
__device__ __forceinline__ unsigned short f2bf(float f) {
  union { float f; unsigned int i; } v; v.f = f;
  unsigned int r = v.i + 0x7fffu + ((v.i >> 16) & 1u);  // RNE
  return (unsigned short)(r >> 16);
}

// ---- dtype probe: bf16 arrays have sane exponents at every index; fp32 read
// ---- as ushort has uniform-random exponent bits at even indices. flag=1 -> fp32
__global__ void detect_dtype(const unsigned short* __restrict__ hs, int* __restrict__ flag) {
  int bad = 0;
  for (int i = 0; i < 128; i += 2) {
    const int e = (hs[i] >> 7) & 0xFF;
    if (e < 100 || e > 140) bad++;
  }
  *flag = (bad > 16) ? 1 : 0;
}

__global__ void to_bf16_any(const void* __restrict__ in, unsigned short* __restrict__ out,
                            int n4, const int* __restrict__ flag) {
  const int i = blockIdx.x * blockDim.x + threadIdx.x;
  if (i >= n4) return;
  if (*flag) {
    const float4 f = ((const float4*)in)[i];
    ushort4 u; u.x = f2bf(f.x); u.y = f2bf(f.y); u.z = f2bf(f.z); u.w = f2bf(f.w);
    ((ushort4*)out)[i] = u;
  } else {
    ((ushort4*)out)[i] = ((const ushort4*)in)[i];
  }
}

__global__ void to_f32_any(const void* __restrict__ in, float* __restrict__ out,
                           int n4, const int* __restrict__ flag) {
  const int i = blockIdx.x * blockDim.x + threadIdx.x;
  if (i >= n4) return;
  if (*flag) {
    ((float4*)out)[i] = ((const float4*)in)[i];
  } else {
    const ushort4 u = ((const ushort4*)in)[i];
    float4 f; f.x = bf2f(u.x); f.y = bf2f(u.y); f.z = bf2f(u.z); f.w = bf2f(u.w);
    ((float4*)out)[i] = f;
  }
}

// ---- transpose + convert: out[c][r] (bf16) = in[r][c]; in is R x C ----
__global__ void transpose_any(const void* __restrict__ in, unsigned short* __restrict__ out,
                              int R, int C, const int* __restrict__ flag) {
  __shared__ unsigned short t[32][36];
  const int r0 = blockIdx.y * 32, c0 = blockIdx.x * 32;
  const int lr = threadIdx.x >> 3;
  const int lc = (threadIdx.x & 7) << 2;
  unsigned short v0, v1, v2, v3;
  if (*flag) {
    const float4 f = *(const float4*)((const float*)in + (size_t)(r0 + lr) * C + c0 + lc);
    v0 = f2bf(f.x); v1 = f2bf(f.y); v2 = f2bf(f.z); v3 = f2bf(f.w);
  } else {
    const ushort4 u = *(const ushort4*)((const unsigned short*)in + (size_t)(r0 + lr) * C + c0 + lc);
    v0 = u.x; v1 = u.y; v2 = u.z; v3 = u.w;
  }
  t[lr][lc] = v0; t[lr][lc + 1] = v1; t[lr][lc + 2] = v2; t[lr][lc + 3] = v3;
  __syncthreads();
  unsigned short* op = out + (size_t)(c0 + lr) * R + r0 + lc;
  ushort4 w;
  w.x = t[lc][lr]; w.y = t[lc + 1][lr]; w.z = t[lc + 2][lr]; w.w = t[lc + 3][lr];
  *(ushort4*)op = w;
}

// ------------- C = A(MxK) * Bt(NxK)^T (+bias), bf16 in, fp32 acc --------------
// m97 structure: 128x128 tile, BK=32, async global->LDS staging (width=16).
__global__ __launch_bounds__(256, 2)
void gemm_bt(const unsigned short* __restrict__ A,
             const unsigned short* __restrict__ Bt,
             const float* __restrict__ bias,
             void* __restrict__ C,
             int M, int N, int K, const int* __restrict__ of32) {
  __shared__ __attribute__((aligned(16))) unsigned short As[128 * 32];
  __shared__ __attribute__((aligned(16))) unsigned short Bs[128 * 32];
  const int tid  = threadIdx.x;
  const int wave = tid >> 6, lane = tid & 63;
  const int quad = lane >> 4, l16 = lane & 15;
  const int m0 = blockIdx.y * 128, n0 = blockIdx.x * 128;
  const int wm = (wave >> 1) * 64, wn = (wave & 1) * 64;

  // thread t owns 16B chunk t: row=t/4, kcol=(t%4)*8; LDS linear = t*16B (= row*32+kcol)
  const int crow = tid >> 2, ck = (tid & 3) << 3;
  const unsigned short* gA = A + (size_t)(m0 + crow) * K + ck;
  const unsigned short* gB = Bt + (size_t)(n0 + crow) * K + ck;
  unsigned short* lA = As + tid * 8;
  unsigned short* lB = Bs + tid * 8;

  f32x4 acc[4][4] = {};

  for (int k0 = 0; k0 < K; k0 += 32) {
    __syncthreads();                 // prev iter's LDS reads done
    ASYNC16(gA + k0, lA);
    ASYNC16(gA + (size_t)64 * K + k0, lA + 64 * 32);
    ASYNC16(gB + k0, lB);
    ASYNC16(gB + (size_t)64 * K + k0, lB + 64 * 32);
    __syncthreads();                 // drains vmcnt: tile visible
    bf16x8 aF[4], bF[4];
#pragma unroll
    for (int i = 0; i < 4; i++)
      aF[i] = *(const bf16x8*)&As[(wm + i * 16 + l16) * 32 + quad * 8];
#pragma unroll
    for (int j = 0; j < 4; j++)
      bF[j] = *(const bf16x8*)&Bs[(wn + j * 16 + l16) * 32 + quad * 8];
#pragma unroll
    for (int i = 0; i < 4; i++)
#pragma unroll
      for (int j = 0; j < 4; j++)
        acc[i][j] = __builtin_amdgcn_mfma_f32_16x16x32_bf16(aF[i], bF[j], acc[i][j], 0, 0, 0);
  }

  const int wf32 = of32 ? *of32 : 0;
#pragma unroll
  for (int j = 0; j < 4; j++) {
    const int col = n0 + wn + j * 16 + l16;
    const float bv = bias ? bias[col] : 0.0f;
#pragma unroll
    for (int i = 0; i < 4; i++) {
#pragma unroll
      for (int r = 0; r < 4; r++) {
        const int row = m0 + wm + i * 16 + quad * 4 + r;   // C/D: row=quad*4+reg, col=l16
        const float v = acc[i][j][r] + bv;
        const size_t off = (size_t)row * N + col;
        if (wf32) ((float*)C)[off] = v;
        else      ((unsigned short*)C)[off] = f2bf(v);
      }
    }
  }
}

// --------- RoPE (interleaved) + split into Q (scaled), K, V^T buffers ---------
__global__ void rope_split(const unsigned short* __restrict__ qkv,
                           const float* __restrict__ cosb,
                           const float* __restrict__ sinb,
                           unsigned short* __restrict__ qb,
                           unsigned short* __restrict__ kb,
                           unsigned short* __restrict__ vtb) {
  const int s = blockIdx.x;
  const unsigned short* row = qkv + (size_t)s * QKVN;
  const float sc = 0.08838834764831845f * 1.44269504088896341f;  // 1/sqrt(128)*log2(e)
  for (int p = threadIdx.x; p < QKVN / 2; p += blockDim.x) {
    const int col = p << 1;
    const int head = col >> 7;
    const int d = col & 127;
    float x0 = bf2f(row[col]), x1 = bf2f(row[col + 1]);
    float y0 = x0, y1 = x1;
    if (d < 64) {
      const float c  = cosb[s * 64 + (d >> 1)];
      const float sn = sinb[s * 64 + (d >> 1)];
      y0 = x0 * c - x1 * sn;
      y1 = x1 * c + x0 * sn;
    }
    if (head < NQH) {
      const size_t o = (size_t)head * SEQ * HD + (size_t)s * HD + d;
      qb[o] = f2bf(y0 * sc); qb[o + 1] = f2bf(y1 * sc);
    } else if (head < NQH + NKVH) {
      const size_t o = (size_t)(head - NQH) * SEQ * HD + (size_t)s * HD + d;
      kb[o] = f2bf(y0); kb[o + 1] = f2bf(y1);
    } else {
      const size_t o = (size_t)(head - NQH - NKVH) * HD * SEQ + (size_t)d * SEQ + s;
      vtb[o] = f2bf(x0); vtb[o + SEQ] = f2bf(x1);  // V: no rope, transposed
    }
  }
}

// ------------------- causal flash attention, bf16 MFMA ------------------------
// grid (32 heads, 32 q-tiles of 64 rows), heavy-first. 4 waves/block, 16 rows/wave.
// K/V tiles staged in LDS via global_load_lds with XOR chunk swizzle (linear LDS
// dest is forced by the async-load; swizzling the SOURCE chunk spreads frag
// reads over all 32 banks). 42KB LDS -> 3 blocks/CU.
__global__ __launch_bounds__(256, 3)
void attn_fwd(const unsigned short* __restrict__ qb,
              const unsigned short* __restrict__ kb,
              const unsigned short* __restrict__ vtb,
              unsigned short* __restrict__ ob) {
  const int h = blockIdx.x;
  const int qt = 31 - (int)blockIdx.y;            // heavy-first scheduling
  const int tid = threadIdx.x;
  const int wave = tid >> 6, lane = tid & 63;
  const int quad = lane >> 4, l16 = lane & 15;
  const int q0 = qt * 64 + wave * 16;
  const unsigned short* qh  = qb  + (size_t)h * SEQ * HD;
  const unsigned short* kh  = kb  + (size_t)(h >> 4) * SEQ * HD;
  const unsigned short* vth = vtb + (size_t)(h >> 4) * HD * SEQ;

  __shared__ __attribute__((aligned(16))) unsigned short Ks[64 * 128];   // [key][d], chunk-swizzled
  __shared__ __attribute__((aligned(16))) unsigned short Vs[128 * 64];   // [d][key], chunk-swizzled
  __shared__ __attribute__((aligned(16))) unsigned short plds[4][16][80];

  bf16x8 qf[4];
#pragma unroll
  for (int kbk = 0; kbk < 4; kbk++)   // A-frag: A[m=l16][k=quad*8+j]
    qf[kbk] = *(const bf16x8*)&qh[(size_t)(q0 + l16) * HD + kbk * 32 + quad * 8];

  f32x4 oacc[8] = {};
  float mrow[4] = {-1e30f, -1e30f, -1e30f, -1e30f};
  float lrow[4] = {0.f, 0.f, 0.f, 0.f};

  for (int kt = 0; kt <= qt; kt++) {
    const int kbase = kt * 64;
    __syncthreads();                   // all waves done reading prev K/V tiles
    // K tile: 64 rows x 256B; chunk j of 1024: key=j>>4, LDS slot j&15 holds
    // global chunk (j&15)^(key&15)
#pragma unroll
    for (int c = 0; c < 4; c++) {
      const int j = c * 256 + tid;
      const int key = j >> 4;
      const int g = (j & 15) ^ (key & 15);
      ASYNC16(kh + (size_t)(kbase + key) * HD + g * 8, (unsigned short*)Ks + j * 8);
    }
    // V tile: 128 rows x 128B; chunk j of 1024: d=j>>3, slot j&7 holds chunk (j&7)^(d&7)
#pragma unroll
    for (int c = 0; c < 4; c++) {
      const int j = c * 256 + tid;
      const int d = j >> 3;
      const int g = (j & 7) ^ (d & 7);
      ASYNC16(vth + (size_t)d * SEQ + kbase + g * 8, (unsigned short*)Vs + j * 8);
    }
    __syncthreads();                   // vmcnt drained: tiles visible

    f32x4 sv[4] = {};
#pragma unroll
    for (int kbk = 0; kbk < 4; kbk++) {
#pragma unroll
      for (int t = 0; t < 4; t++) {
        // B-frag B[n=key][k=d]; swizzled chunk: (kbk*4+quad)^l16
        bf16x8 kf = *(const bf16x8*)&Ks[(t * 16 + l16) * 128 + (((kbk << 2) + quad) ^ l16) * 8];
        sv[t] = __builtin_amdgcn_mfma_f32_16x16x32_bf16(qf[kbk], kf, sv[t], 0, 0, 0);
      }
    }
    if (kt == qt) {   // diagonal tile masking
#pragma unroll
      for (int t = 0; t < 4; t++) {
        const int key = kbase + t * 16 + l16;
#pragma unroll
        for (int r = 0; r < 4; r++)
          if (key > q0 + quad * 4 + r) sv[t][r] = -1e30f;
      }
    }
    float alpha[4];
#pragma unroll
    for (int r = 0; r < 4; r++) {
      float mx = fmaxf(fmaxf(sv[0][r], sv[1][r]), fmaxf(sv[2][r], sv[3][r]));
#pragma unroll
      for (int off = 8; off; off >>= 1) mx = fmaxf(mx, __shfl_xor(mx, off));
      const float mnew = fmaxf(mrow[r], mx);
      alpha[r] = __builtin_exp2f(mrow[r] - mnew);
      mrow[r] = mnew;
      float ls = 0.f;
#pragma unroll
      for (int t = 0; t < 4; t++) {
        const float pv = __builtin_exp2f(sv[t][r] - mnew);
        sv[t][r] = pv;
        ls += pv;
      }
#pragma unroll
      for (int off = 8; off; off >>= 1) ls += __shfl_xor(ls, off);
      lrow[r] = lrow[r] * alpha[r] + ls;
    }
#pragma unroll
    for (int dt = 0; dt < 8; dt++)
#pragma unroll
      for (int r = 0; r < 4; r++) oacc[dt][r] *= alpha[r];
    // P: C-layout -> A-layout via LDS round-trip (barriers: uniform trip count)
    __syncthreads();
#pragma unroll
    for (int r = 0; r < 4; r++)
#pragma unroll
      for (int t = 0; t < 4; t++)
        plds[wave][quad * 4 + r][t * 16 + l16] = f2bf(sv[t][r]);
    __syncthreads();
    bf16x8 pf0 = *(const bf16x8*)&plds[wave][l16][quad * 8];
    bf16x8 pf1 = *(const bf16x8*)&plds[wave][l16][32 + quad * 8];
#pragma unroll
    for (int dt = 0; dt < 8; dt++) {
      const int vrow = (dt * 16 + l16) * 64;
      bf16x8 vf0 = *(const bf16x8*)&Vs[vrow + ((quad) ^ (l16 & 7)) * 8];
      oacc[dt] = __builtin_amdgcn_mfma_f32_16x16x32_bf16(pf0, vf0, oacc[dt], 0, 0, 0);
      bf16x8 vf1 = *(const bf16x8*)&Vs[vrow + ((4 + quad) ^ (l16 & 7)) * 8];
      oacc[dt] = __builtin_amdgcn_mfma_f32_16x16x32_bf16(pf1, vf1, oacc[dt], 0, 0, 0);
    }
  }
#pragma unroll
  for (int dt = 0; dt < 8; dt++) {
#pragma unroll
    for (int r = 0; r < 4; r++) {
      const float v = oacc[dt][r] / lrow[r];
      ob[(size_t)(q0 + quad * 4 + r) * ATTN_N + h * HD + dt * 16 + l16] = f2bf(v);
    }
  }
}

extern "C" void kernel_launch(void* const* d_in, const int* in_sizes, int n_in,
                              void* d_out, int out_size, void* d_ws, size_t ws_size,
                              hipStream_t stream) {
  const void* hs_raw   = d_in[0];
  const void* cos_raw  = d_in[1];
  const void* sin_raw  = d_in[2];
  const void* wqkv_raw = d_in[3];
  const void* bqkv_raw = d_in[4];
  const void* wo_raw   = d_in[5];
  unsigned short* ws = (unsigned short*)d_ws;

  unsigned short* R1   = ws;                           // wt_qkv -> q/k/vt bufs -> wt_o
  unsigned short* R2   = R1 + (size_t)QKVN * HIDDEN;   // qkv -> attnb
  unsigned short* hs_c = R2 + (size_t)SEQ * QKVN;
  float* cosf  = (float*)(hs_c + (size_t)SEQ * HIDDEN);
  float* sinf  = cosf + SEQ * 64;
  float* biasf = sinf + SEQ * 64;
  int*   flag  = (int*)(biasf + QKVN);

  unsigned short* wt_qkv = R1;
  unsigned short* qbuf   = R1;
  unsigned short* kbuf   = qbuf + (size_t)NQH * SEQ * HD;
  unsigned short* vtbuf  = kbuf + (size_t)NKVH * SEQ * HD;
  unsigned short* wt_o   = R1;
  unsigned short* qkv    = R2;
  unsigned short* attnb  = R2;

  detect_dtype<<<1, 1, 0, stream>>>((const unsigned short*)hs_raw, flag);
  to_bf16_any<<<(SEQ * HIDDEN / 4 + 255) / 256, 256, 0, stream>>>(hs_raw, hs_c, SEQ * HIDDEN / 4, flag);
  to_f32_any<<<(SEQ * 64 / 4 + 255) / 256, 256, 0, stream>>>(cos_raw, cosf, SEQ * 64 / 4, flag);
  to_f32_any<<<(SEQ * 64 / 4 + 255) / 256, 256, 0, stream>>>(sin_raw, sinf, SEQ * 64 / 4, flag);
  to_f32_any<<<(QKVN / 4 + 255) / 256, 256, 0, stream>>>(bqkv_raw, biasf, QKVN / 4, flag);

  transpose_any<<<dim3(QKVN / 32, HIDDEN / 32), 256, 0, stream>>>(wqkv_raw, wt_qkv, HIDDEN, QKVN, flag);
  gemm_bt<<<dim3(QKVN / 128, SEQ / 128), 256, 0, stream>>>(hs_c, wt_qkv, biasf, qkv, SEQ, QKVN, HIDDEN, nullptr);
  rope_split<<<SEQ, 256, 0, stream>>>(qkv, cosf, sinf, qbuf, kbuf, vtbuf);
  attn_fwd<<<dim3(NQH, SEQ / 64), 256, 0, stream>>>(qbuf, kbuf, vtbuf, attnb);
  transpose_any<<<dim3(ATTN_N / 32, HIDDEN / 32), 256, 0, stream>>>(wo_raw, wt_o, HIDDEN, ATTN_N, flag);
  gemm_bt<<<dim3(ATTN_N / 128, SEQ / 128), 256, 0, stream>>>(attnb, wt_o, nullptr, d_out, SEQ, ATTN_N, HIDDEN, flag);
}

// Round 5
// 493.082 us; speedup vs baseline: 1.5335x; 1.0283x over previous
//
#include <hip/hip_runtime.h>
#include <stdint.h>

#define SEQ    2048
#define HIDDEN 4096
#define NQH    32
#define NKVH   2
#define HD     128
#define QKVN   4608   // (32+4)*128
#define ATTN_N 4096   // 32*128

typedef short bf16x8 __attribute__((ext_vector_type(8)));
typedef float f32x4  __attribute__((ext_vector_type(4)));

#define ASYNC16(gp, lp) __builtin_amdgcn_global_load_lds( \
    (const __attribute__((address_space(1))) void*)(gp),  \
    (__attribute__((address_space(3))) void*)(lp), 16, 0, 0)

__device__ __forceinline__ float bf2f(unsigned short u) {
  union { unsigned int i; float f; } v; v.i = ((unsigned int)u) << 16; return v.f;
}
__device__ __forceinline__ unsigned short f2bf(float f) {
  union { float f; unsigned int i; } v; v.f = f;
  unsigned int r = v.i + 0x7fffu + ((v.i >> 16) & 1u);  // RNE
  return (unsigned short)(r >> 16);
}

// ---- dtype probe: bf16 arrays have sane exponents at every index; fp32 read
// ---- as ushort has uniform-random exponent bits at even indices. flag=1 -> fp32
__global__ void detect_dtype(const unsigned short* __restrict__ hs, int* __restrict__ flag) {
  int bad = 0;
  for (int i = 0; i < 128; i += 2) {
    const int e = (hs[i] >> 7) & 0xFF;
    if (e < 100 || e > 140) bad++;
  }
  *flag = (bad > 16) ? 1 : 0;
}

__global__ void to_bf16_any(const void* __restrict__ in, unsigned short* __restrict__ out,
                            int n4, const int* __restrict__ flag) {
  const int i = blockIdx.x * blockDim.x + threadIdx.x;
  if (i >= n4) return;
  if (*flag) {
    const float4 f = ((const float4*)in)[i];
    ushort4 u; u.x = f2bf(f.x); u.y = f2bf(f.y); u.z = f2bf(f.z); u.w = f2bf(f.w);
    ((ushort4*)out)[i] = u;
  } else {
    ((ushort4*)out)[i] = ((const ushort4*)in)[i];
  }
}

__global__ void to_f32_any(const void* __restrict__ in, float* __restrict__ out,
                           int n4, const int* __restrict__ flag) {
  const int i = blockIdx.x * blockDim.x + threadIdx.x;
  if (i >= n4) return;
  if (*flag) {
    ((float4*)out)[i] = ((const float4*)in)[i];
  } else {
    const ushort4 u = ((const ushort4*)in)[i];
    float4 f; f.x = bf2f(u.x); f.y = bf2f(u.y); f.z = bf2f(u.z); f.w = bf2f(u.w);
    ((float4*)out)[i] = f;
  }
}

// ---- transpose + convert: out[c][r] (bf16) = in[r][c]; in is R x C ----
__global__ void transpose_any(const void* __restrict__ in, unsigned short* __restrict__ out,
                              int R, int C, const int* __restrict__ flag) {
  __shared__ unsigned short t[32][36];
  const int r0 = blockIdx.y * 32, c0 = blockIdx.x * 32;
  const int lr = threadIdx.x >> 3;
  const int lc = (threadIdx.x & 7) << 2;
  unsigned short v0, v1, v2, v3;
  if (*flag) {
    const float4 f = *(const float4*)((const float*)in + (size_t)(r0 + lr) * C + c0 + lc);
    v0 = f2bf(f.x); v1 = f2bf(f.y); v2 = f2bf(f.z); v3 = f2bf(f.w);
  } else {
    const ushort4 u = *(const ushort4*)((const unsigned short*)in + (size_t)(r0 + lr) * C + c0 + lc);
    v0 = u.x; v1 = u.y; v2 = u.z; v3 = u.w;
  }
  t[lr][lc] = v0; t[lr][lc + 1] = v1; t[lr][lc + 2] = v2; t[lr][lc + 3] = v3;
  __syncthreads();
  unsigned short* op = out + (size_t)(c0 + lr) * R + r0 + lc;
  ushort4 w;
  w.x = t[lc][lr]; w.y = t[lc + 1][lr]; w.z = t[lc + 2][lr]; w.w = t[lc + 3][lr];
  *(ushort4*)op = w;
}

// ------------- C = A(MxK) * Bt(NxK)^T (+bias), bf16 in, fp32 acc --------------
// m97 structure: 128x128 tile, BK=32, async global->LDS staging (width=16).
// XOR k-chunk swizzle (source-side; LDS dest linear): frag-read bank-start
// = (l16&1)*16 + (quad^((l16>>1)&3))*4 -> all 8 bank-quads x2 = conflict-free.
__global__ __launch_bounds__(256, 2)
void gemm_bt(const unsigned short* __restrict__ A,
             const unsigned short* __restrict__ Bt,
             const float* __restrict__ bias,
             void* __restrict__ C,
             int M, int N, int K, const int* __restrict__ of32) {
  __shared__ __attribute__((aligned(16))) unsigned short As[128 * 32];
  __shared__ __attribute__((aligned(16))) unsigned short Bs[128 * 32];
  const int tid  = threadIdx.x;
  const int wave = tid >> 6, lane = tid & 63;
  const int quad = lane >> 4, l16 = lane & 15;
  const int m0 = blockIdx.y * 128, n0 = blockIdx.x * 128;
  const int wm = (wave >> 1) * 64, wn = (wave & 1) * 64;

  // thread t stages row=t/4, swizzled k-chunk g=(t&3)^((row>>1)&3); LDS = t*16B
  const int crow = tid >> 2;
  const int gsw = ((tid & 3) ^ ((crow >> 1) & 3)) << 3;
  const unsigned short* gA = A + (size_t)(m0 + crow) * K + gsw;
  const unsigned short* gB = Bt + (size_t)(n0 + crow) * K + gsw;
  unsigned short* lA = As + tid * 8;
  unsigned short* lB = Bs + tid * 8;

  // frag-read swizzled chunk offset (elements)
  const int cxor = (quad ^ ((l16 >> 1) & 3)) << 3;

  f32x4 acc[4][4] = {};

  for (int k0 = 0; k0 < K; k0 += 32) {
    __syncthreads();                 // prev iter's LDS reads done
    ASYNC16(gA + k0, lA);
    ASYNC16(gA + (size_t)64 * K + k0, lA + 64 * 32);
    ASYNC16(gB + k0, lB);
    ASYNC16(gB + (size_t)64 * K + k0, lB + 64 * 32);
    __syncthreads();                 // drains vmcnt: tile visible
    bf16x8 aF[4], bF[4];
#pragma unroll
    for (int i = 0; i < 4; i++)
      aF[i] = *(const bf16x8*)&As[(wm + i * 16 + l16) * 32 + cxor];
#pragma unroll
    for (int j = 0; j < 4; j++)
      bF[j] = *(const bf16x8*)&Bs[(wn + j * 16 + l16) * 32 + cxor];
#pragma unroll
    for (int i = 0; i < 4; i++)
#pragma unroll
      for (int j = 0; j < 4; j++)
        acc[i][j] = __builtin_amdgcn_mfma_f32_16x16x32_bf16(aF[i], bF[j], acc[i][j], 0, 0, 0);
  }

  const int wf32 = of32 ? *of32 : 0;
#pragma unroll
  for (int j = 0; j < 4; j++) {
    const int col = n0 + wn + j * 16 + l16;
    const float bv = bias ? bias[col] : 0.0f;
#pragma unroll
    for (int i = 0; i < 4; i++) {
#pragma unroll
      for (int r = 0; r < 4; r++) {
        const int row = m0 + wm + i * 16 + quad * 4 + r;   // C/D: row=quad*4+reg, col=l16
        const float v = acc[i][j][r] + bv;
        const size_t off = (size_t)row * N + col;
        if (wf32) ((float*)C)[off] = v;
        else      ((unsigned short*)C)[off] = f2bf(v);
      }
    }
  }
}

// --------- RoPE (interleaved) + split into Q (scaled), K, V^T buffers ---------
__global__ void rope_split(const unsigned short* __restrict__ qkv,
                           const float* __restrict__ cosb,
                           const float* __restrict__ sinb,
                           unsigned short* __restrict__ qb,
                           unsigned short* __restrict__ kb,
                           unsigned short* __restrict__ vtb) {
  const int s = blockIdx.x;
  const unsigned short* row = qkv + (size_t)s * QKVN;
  const float sc = 0.08838834764831845f * 1.44269504088896341f;  // 1/sqrt(128)*log2(e)
  for (int p = threadIdx.x; p < QKVN / 2; p += blockDim.x) {
    const int col = p << 1;
    const int head = col >> 7;
    const int d = col & 127;
    float x0 = bf2f(row[col]), x1 = bf2f(row[col + 1]);
    float y0 = x0, y1 = x1;
    if (d < 64) {
      const float c  = cosb[s * 64 + (d >> 1)];
      const float sn = sinb[s * 64 + (d >> 1)];
      y0 = x0 * c - x1 * sn;
      y1 = x1 * c + x0 * sn;
    }
    if (head < NQH) {
      const size_t o = (size_t)head * SEQ * HD + (size_t)s * HD + d;
      qb[o] = f2bf(y0 * sc); qb[o + 1] = f2bf(y1 * sc);
    } else if (head < NQH + NKVH) {
      const size_t o = (size_t)(head - NQH) * SEQ * HD + (size_t)s * HD + d;
      kb[o] = f2bf(y0); kb[o + 1] = f2bf(y1);
    } else {
      const size_t o = (size_t)(head - NQH - NKVH) * HD * SEQ + (size_t)d * SEQ + s;
      vtb[o] = f2bf(x0); vtb[o + SEQ] = f2bf(x1);  // V: no rope, transposed
    }
  }
}

// ------------------- causal flash attention, bf16 MFMA ------------------------
// grid (32 heads, 32 q-tiles of 64 rows), heavy-first. 4 waves/block, 16 rows/wave.
// K/V staged in LDS via global_load_lds with XOR chunk swizzle. Row-sums of P
// computed by an extra MFMA against an all-ones B-frag (replaces shuffle tree).
__global__ __launch_bounds__(256, 3)
void attn_fwd(const unsigned short* __restrict__ qb,
              const unsigned short* __restrict__ kb,
              const unsigned short* __restrict__ vtb,
              unsigned short* __restrict__ ob) {
  const int h = blockIdx.x;
  const int qt = 31 - (int)blockIdx.y;            // heavy-first scheduling
  const int tid = threadIdx.x;
  const int wave = tid >> 6, lane = tid & 63;
  const int quad = lane >> 4, l16 = lane & 15;
  const int q0 = qt * 64 + wave * 16;
  const unsigned short* qh  = qb  + (size_t)h * SEQ * HD;
  const unsigned short* kh  = kb  + (size_t)(h >> 4) * SEQ * HD;
  const unsigned short* vth = vtb + (size_t)(h >> 4) * HD * SEQ;

  __shared__ __attribute__((aligned(16))) unsigned short Ks[64 * 128];   // [key][d], chunk-swizzled
  __shared__ __attribute__((aligned(16))) unsigned short Vs[128 * 64];   // [d][key], chunk-swizzled
  __shared__ __attribute__((aligned(16))) unsigned short plds[4][16][80];

  bf16x8 qf[4];
#pragma unroll
  for (int kbk = 0; kbk < 4; kbk++)   // A-frag: A[m=l16][k=quad*8+j]
    qf[kbk] = *(const bf16x8*)&qh[(size_t)(q0 + l16) * HD + kbk * 32 + quad * 8];

  bf16x8 onesf;
#pragma unroll
  for (int i = 0; i < 8; i++) onesf[i] = (short)0x3F80;   // bf16 1.0

  f32x4 oacc[8] = {};
  f32x4 lacc = {};
  float mrow[4] = {-1e30f, -1e30f, -1e30f, -1e30f};

  for (int kt = 0; kt <= qt; kt++) {
    const int kbase = kt * 64;
    __syncthreads();                   // all waves done reading prev K/V tiles
    // K tile: chunk j of 1024: key=j>>4, LDS slot j&15 holds global chunk (j&15)^(key&15)
#pragma unroll
    for (int c = 0; c < 4; c++) {
      const int j = c * 256 + tid;
      const int key = j >> 4;
      const int g = (j & 15) ^ (key & 15);
      ASYNC16(kh + (size_t)(kbase + key) * HD + g * 8, (unsigned short*)Ks + j * 8);
    }
    // V tile: chunk j of 1024: d=j>>3, slot j&7 holds chunk (j&7)^(d&7)
#pragma unroll
    for (int c = 0; c < 4; c++) {
      const int j = c * 256 + tid;
      const int d = j >> 3;
      const int g = (j & 7) ^ (d & 7);
      ASYNC16(vth + (size_t)d * SEQ + kbase + g * 8, (unsigned short*)Vs + j * 8);
    }
    __syncthreads();                   // vmcnt drained: tiles visible

    f32x4 sv[4] = {};
#pragma unroll
    for (int kbk = 0; kbk < 4; kbk++) {
#pragma unroll
      for (int t = 0; t < 4; t++) {
        bf16x8 kf = *(const bf16x8*)&Ks[(t * 16 + l16) * 128 + (((kbk << 2) + quad) ^ l16) * 8];
        sv[t] = __builtin_amdgcn_mfma_f32_16x16x32_bf16(qf[kbk], kf, sv[t], 0, 0, 0);
      }
    }
    if (kt == qt) {   // diagonal tile masking
#pragma unroll
      for (int t = 0; t < 4; t++) {
        const int key = kbase + t * 16 + l16;
#pragma unroll
        for (int r = 0; r < 4; r++)
          if (key > q0 + quad * 4 + r) sv[t][r] = -1e30f;
      }
    }
    float alpha[4];
#pragma unroll
    for (int r = 0; r < 4; r++) {
      float mx = fmaxf(fmaxf(sv[0][r], sv[1][r]), fmaxf(sv[2][r], sv[3][r]));
#pragma unroll
      for (int off = 8; off; off >>= 1) mx = fmaxf(mx, __shfl_xor(mx, off));
      const float mnew = fmaxf(mrow[r], mx);
      alpha[r] = __builtin_exp2f(mrow[r] - mnew);
      mrow[r] = mnew;
#pragma unroll
      for (int t = 0; t < 4; t++)
        sv[t][r] = __builtin_exp2f(sv[t][r] - mnew);
    }
#pragma unroll
    for (int dt = 0; dt < 8; dt++)
#pragma unroll
      for (int r = 0; r < 4; r++) oacc[dt][r] *= alpha[r];
#pragma unroll
    for (int r = 0; r < 4; r++) lacc[r] *= alpha[r];
    // P: C-layout -> A-layout via LDS round-trip (barriers: uniform trip count)
    __syncthreads();
#pragma unroll
    for (int r = 0; r < 4; r++)
#pragma unroll
      for (int t = 0; t < 4; t++)
        plds[wave][quad * 4 + r][t * 16 + l16] = f2bf(sv[t][r]);
    __syncthreads();
    bf16x8 pf0 = *(const bf16x8*)&plds[wave][l16][quad * 8];
    bf16x8 pf1 = *(const bf16x8*)&plds[wave][l16][32 + quad * 8];
    // row-sum of P via ones B-frag: lacc[r] += sum_k P[row][k] (replicated over l16)
    lacc = __builtin_amdgcn_mfma_f32_16x16x32_bf16(pf0, onesf, lacc, 0, 0, 0);
    lacc = __builtin_amdgcn_mfma_f32_16x16x32_bf16(pf1, onesf, lacc, 0, 0, 0);
#pragma unroll
    for (int dt = 0; dt < 8; dt++) {
      const int vrow = (dt * 16 + l16) * 64;
      bf16x8 vf0 = *(const bf16x8*)&Vs[vrow + ((quad) ^ (l16 & 7)) * 8];
      oacc[dt] = __builtin_amdgcn_mfma_f32_16x16x32_bf16(pf0, vf0, oacc[dt], 0, 0, 0);
      bf16x8 vf1 = *(const bf16x8*)&Vs[vrow + ((4 + quad) ^ (l16 & 7)) * 8];
      oacc[dt] = __builtin_amdgcn_mfma_f32_16x16x32_bf16(pf1, vf1, oacc[dt], 0, 0, 0);
    }
  }
#pragma unroll
  for (int dt = 0; dt < 8; dt++) {
#pragma unroll
    for (int r = 0; r < 4; r++) {
      const float v = oacc[dt][r] / lacc[r];
      ob[(size_t)(q0 + quad * 4 + r) * ATTN_N + h * HD + dt * 16 + l16] = f2bf(v);
    }
  }
}

extern "C" void kernel_launch(void* const* d_in, const int* in_sizes, int n_in,
                              void* d_out, int out_size, void* d_ws, size_t ws_size,
                              hipStream_t stream) {
  const void* hs_raw   = d_in[0];
  const void* cos_raw  = d_in[1];
  const void* sin_raw  = d_in[2];
  const void* wqkv_raw = d_in[3];
  const void* bqkv_raw = d_in[4];
  const void* wo_raw   = d_in[5];
  unsigned short* ws = (unsigned short*)d_ws;

  unsigned short* R1   = ws;                           // wt_qkv -> q/k/vt bufs -> wt_o
  unsigned short* R2   = R1 + (size_t)QKVN * HIDDEN;   // qkv -> attnb
  unsigned short* hs_c = R2 + (size_t)SEQ * QKVN;
  float* cosf  = (float*)(hs_c + (size_t)SEQ * HIDDEN);
  float* sinf  = cosf + SEQ * 64;
  float* biasf = sinf + SEQ * 64;
  int*   flag  = (int*)(biasf + QKVN);

  unsigned short* wt_qkv = R1;
  unsigned short* qbuf   = R1;
  unsigned short* kbuf   = qbuf + (size_t)NQH * SEQ * HD;
  unsigned short* vtbuf  = kbuf + (size_t)NKVH * SEQ * HD;
  unsigned short* wt_o   = R1;
  unsigned short* qkv    = R2;
  unsigned short* attnb  = R2;

  detect_dtype<<<1, 1, 0, stream>>>((const unsigned short*)hs_raw, flag);
  to_bf16_any<<<(SEQ * HIDDEN / 4 + 255) / 256, 256, 0, stream>>>(hs_raw, hs_c, SEQ * HIDDEN / 4, flag);
  to_f32_any<<<(SEQ * 64 / 4 + 255) / 256, 256, 0, stream>>>(cos_raw, cosf, SEQ * 64 / 4, flag);
  to_f32_any<<<(SEQ * 64 / 4 + 255) / 256, 256, 0, stream>>>(sin_raw, sinf, SEQ * 64 / 4, flag);
  to_f32_any<<<(QKVN / 4 + 255) / 256, 256, 0, stream>>>(bqkv_raw, biasf, QKVN / 4, flag);

  transpose_any<<<dim3(QKVN / 32, HIDDEN / 32), 256, 0, stream>>>(wqkv_raw, wt_qkv, HIDDEN, QKVN, flag);
  gemm_bt<<<dim3(QKVN / 128, SEQ / 128), 256, 0, stream>>>(hs_c, wt_qkv, biasf, qkv, SEQ, QKVN, HIDDEN, nullptr);
  rope_split<<<SEQ, 256, 0, stream>>>(qkv, cosf, sinf, qbuf, kbuf, vtbuf);
  attn_fwd<<<dim3(NQH, SEQ / 64), 256, 0, stream>>>(qbuf, kbuf, vtbuf, attnb);
  transpose_any<<<dim3(ATTN_N / 32, HIDDEN / 32), 256, 0, stream>>>(wo_raw, wt_o, HIDDEN, ATTN_N, flag);
  gemm_bt<<<dim3(ATTN_N / 128, SEQ / 128), 256, 0, stream>>>(attnb, wt_o, nullptr, d_out, SEQ, ATTN_N, HIDDEN, flag);
}